// Round 13
// baseline (318.336 us; speedup 1.0000x reference)
//
#include <hip/hip_runtime.h>

#define DIM 128
#define BN_EPS 1e-5f
#define BCAP 8192        // per-bucket capacity (mean ~4082 for E=800k, NB=196)
#define EPB 4096         // edges per k_bin block
#define EPT 16           // edges per thread in k_bin

typedef __bf16 bf16x8 __attribute__((ext_vector_type(8)));
typedef float f32x4 __attribute__((ext_vector_type(4)));
typedef float f32x2 __attribute__((ext_vector_type(2)));

__device__ __forceinline__ float bf_e0(unsigned int u) {
    return __builtin_bit_cast(float, u << 16);
}
__device__ __forceinline__ float bf_e1(unsigned int u) {
    return __builtin_bit_cast(float, u & 0xffff0000u);
}
__device__ __forceinline__ unsigned short f2b(float f) {
    __bf16 b = (__bf16)f;  // RTN hardware convert
    return __builtin_bit_cast(unsigned short, b);
}
__device__ __forceinline__ unsigned int pack2(float lo, float hi) {
    return (unsigned int)f2b(lo) | ((unsigned int)f2b(hi) << 16);
}

// async global->LDS, 16B per lane: lds base is wave-uniform, gsrc per-lane.
#define GLOAD_LDS16(gsrc, ldst)                                               \
    __builtin_amdgcn_global_load_lds(                                         \
        (const __attribute__((address_space(1))) void*)(gsrc),                \
        (__attribute__((address_space(3))) void*)(ldst), 16, 0, 0)

// ---------------- pass 1: bin edges by dst>>8 + weight transform tail -------
// entry: (dst&255)<<17 | src   (requires N <= 2^17)
__global__ __launch_bounds__(256) void k_bin(const int* __restrict__ src,
                                             const int* __restrict__ dst,
                                             int* __restrict__ cursor,
                                             unsigned int* __restrict__ binned,
                                             const float* __restrict__ Wp,
                                             const float* __restrict__ Wl,
                                             const float* __restrict__ Wr,
                                             unsigned short* __restrict__ WTf,
                                             int E, int NB) {
    __shared__ int hist[256];
    __shared__ int base[256];
    __shared__ int c2[256];
    const int tid = threadIdx.x;
    const int e0 = blockIdx.x * EPB;

    unsigned int u[EPT];
    int b[EPT];
    hist[tid] = 0;
    c2[tid] = 0;
    __syncthreads();
#pragma unroll
    for (int i = 0; i < EPT; ++i) {
        int e = e0 + i * 256 + tid;
        if (e < E) {
            int d = dst[e];
            b[i] = d >> 8;
            u[i] = ((unsigned int)(d & 255) << 17) | (unsigned int)src[e];
            atomicAdd(&hist[b[i]], 1);
        } else {
            b[i] = -1;
        }
    }
    __syncthreads();
    if (tid < NB && hist[tid] > 0) base[tid] = atomicAdd(&cursor[tid], hist[tid]);
    __syncthreads();
#pragma unroll
    for (int i = 0; i < EPT; ++i) {
        if (b[i] < 0) continue;
        int p = base[b[i]] + atomicAdd(&c2[b[i]], 1);
        if (p < BCAP) binned[(size_t)b[i] * BCAP + p] = u[i];
    }

    // ---- tail: weights -> bf16 FRAGMENT-MAJOR (first 72 blocks) ----
    // WTf[m]: frag (ct,k,lane) at ((ct*4+k)*64+lane)*8 holding
    // W^T[ct*16+(lane&15)][k*32+(lane>>4)*8+e], e=0..7 (A-operand layout).
    int gid = blockIdx.x * 256 + tid;
    if (gid < 9 * 2048) {
        int m = gid >> 11;
        int r = gid & 2047;
        int lane = r & 63;
        int k = (r >> 6) & 3;
        int ct = r >> 8;
        int feat = ct * 16 + (lane & 15);
        int kb = k * 32 + (lane >> 4) * 8;
        const float* W = (m == 0) ? Wp : (m < 5) ? (Wl + (size_t)(m - 1) * DIM * DIM)
                                                 : (Wr + (size_t)(m - 5) * DIM * DIM);
        unsigned short o[8];
#pragma unroll
        for (int e = 0; e < 8; ++e) o[e] = f2b(W[(size_t)(kb + e) * DIM + feat]);
        *(uint4*)(WTf + (size_t)gid * 8) = *(const uint4*)o;
    }
}

// ---------------- pass 2: per-bucket CSR; each block scans bucket counts ----
__global__ __launch_bounds__(256) void k_csr(const int* __restrict__ cursor,
                                             const unsigned int* __restrict__ binned,
                                             int* __restrict__ rowptr,
                                             float* __restrict__ inv_deg,
                                             int* __restrict__ col, int N, int NB) {
    __shared__ unsigned int stage[BCAP];   // 32 KB
    __shared__ int deg[256];
    __shared__ int start[256];
    __shared__ int sh[256];
    const int b = blockIdx.x;
    const int t = threadIdx.x;
    const int node0 = b << 8;

    int v = (t < NB) ? min(cursor[t], BCAP) : 0;
    sh[t] = v;
    deg[t] = 0;
    __syncthreads();
    for (int off = 1; off < 256; off <<= 1) {
        int a = (t >= off) ? sh[t - off] : 0;
        __syncthreads();
        sh[t] += a;
        __syncthreads();
    }
    const int gbase = sh[b] - min(cursor[b], BCAP);
    const int cnt = min(cursor[b], BCAP);
    if (b == 0 && t == 255) rowptr[N] = sh[255];

    for (int e = t; e < cnt; e += 256) {
        unsigned int u = binned[(size_t)b * BCAP + e];
        stage[e] = u;
        atomicAdd(&deg[u >> 17], 1);
    }
    __syncthreads();
    int d = deg[t];
    start[t] = d;
    __syncthreads();
    for (int off = 1; off < 256; off <<= 1) {
        int a = (t >= off) ? start[t - off] : 0;
        __syncthreads();
        start[t] += a;
        __syncthreads();
    }
    int excl = start[t] - d;
    int node = node0 + t;
    if (node < N) {
        rowptr[node] = gbase + excl;
        inv_deg[node] = 1.0f / (float)(d > 1 ? d : 1);
    }
    __syncthreads();
    deg[t] = excl;  // reuse as running cursor
    __syncthreads();
    for (int e = t; e < cnt; e += 256) {
        unsigned int u = stage[e];
        int dl = u >> 17;
        int p = atomicAdd(&deg[dl], 1);
        col[gbase + p] = (int)(u & 0x1ffffu);
    }
}

// ---------------- projection GEMM: x = relu(x_in @ Wp + bp) -> bf16 + fp8 ----
__global__ __launch_bounds__(256) void k_proj(
    const float* __restrict__ Ain, const unsigned short* __restrict__ Wf,
    const float* __restrict__ bias,
    unsigned short* __restrict__ outb, unsigned char* __restrict__ out8,
    int nrows) {
    __shared__ unsigned short wlds[16384];  // 32 KB

    const int tid = threadIdx.x;
    const int lane = tid & 63;
    const int l15 = lane & 15;
    const int lhi = lane >> 4;
    const int wave = tid >> 6;
    const int node = blockIdx.x * 64 + wave * 16 + l15;
    const int arow = node < nrows ? node : nrows - 1;

    // A frags (fp32 -> bf16), issued before staging
    bf16x8 af[4];
    {
        const float* a0 = Ain + (size_t)arow * DIM + lhi * 8;
#pragma unroll
        for (int k = 0; k < 4; ++k) {
            float4 v0 = *(const float4*)(a0 + k * 32);
            float4 v1 = *(const float4*)(a0 + k * 32 + 4);
            bf16x8 f;
            f[0] = (__bf16)v0.x; f[1] = (__bf16)v0.y;
            f[2] = (__bf16)v0.z; f[3] = (__bf16)v0.w;
            f[4] = (__bf16)v1.x; f[5] = (__bf16)v1.y;
            f[6] = (__bf16)v1.z; f[7] = (__bf16)v1.w;
            af[k] = f;
        }
    }
    {
        const unsigned short* g = Wf + (size_t)wave * 4096 + lane * 8;
#pragma unroll
        for (int i = 0; i < 8; ++i)
            GLOAD_LDS16(g + i * 512, &wlds[wave * 4096 + i * 512]);
    }

    f32x4 acc[8];
#pragma unroll
    for (int ct = 0; ct < 8; ++ct) acc[ct] = (f32x4){0.f, 0.f, 0.f, 0.f};

    __syncthreads();

#pragma unroll
    for (int k = 0; k < 4; ++k) {
        bf16x8 bw[8];
#pragma unroll
        for (int ct = 0; ct < 8; ++ct)
            bw[ct] = *(const bf16x8*)&wlds[((ct * 4 + k) * 64 + lane) * 8];
#pragma unroll
        for (int ct = 0; ct < 8; ++ct)
            acc[ct] = __builtin_amdgcn_mfma_f32_16x16x32_bf16(bw[ct], af[k],
                                                              acc[ct], 0, 0, 0);
    }

    if (node < nrows) {
#pragma unroll
        for (int ct = 0; ct < 8; ++ct) {
            int c0 = ct * 16 + lhi * 4;
            float4 bb = *(const float4*)(bias + c0);
            float h[4];
            h[0] = fmaxf(acc[ct][0] + bb.x, 0.f);
            h[1] = fmaxf(acc[ct][1] + bb.y, 0.f);
            h[2] = fmaxf(acc[ct][2] + bb.z, 0.f);
            h[3] = fmaxf(acc[ct][3] + bb.w, 0.f);
            size_t base = (size_t)node * DIM + c0;
            uint2 o;
            o.x = pack2(h[0], h[1]);
            o.y = pack2(h[2], h[3]);
            *(uint2*)(outb + base) = o;
            int w = __builtin_amdgcn_cvt_pk_fp8_f32(h[0], h[1], 0, false);
            w = __builtin_amdgcn_cvt_pk_fp8_f32(h[2], h[3], w, true);
            *(unsigned int*)(out8 + base) = (unsigned int)w;
        }
    }
}

// ---------------- FUSED layer: gather-aggregate + dual GEMM + epilogue -------
// block = 256 thr = 4 waves = 64 nodes; wave owns 16 nodes.
// Phase 1: gather 2 nodes concurrently (8 uint2 gathers in flight = 32 rows),
//          agg rows packed bf16 into LDS atile in MFMA-frag layout
//          (octet-swizzled: slot = octet ^ node -> 2-way banks = free).
// Phase 2: af0 from atile, af1 from xb; W frags streamed from global (L2);
//          64 MFMAs; BN+ReLU+resid epilogue -> xb (in-place) + x8out + out32.
// x8in != x8out (double buffer): fused blocks race on in-place x8 otherwise.
__global__ __launch_bounds__(256) void k_layer(
    const uint2* __restrict__ x8in, const unsigned short* __restrict__ xb,
    const int* __restrict__ rowptr, const int* __restrict__ col,
    const float* __restrict__ inv_deg,
    const unsigned short* __restrict__ Wl, const unsigned short* __restrict__ Wr,
    const float* __restrict__ bias, const float* __restrict__ gamma,
    const float* __restrict__ beta, const float* __restrict__ mean,
    const float* __restrict__ var,
    unsigned short* __restrict__ outb, unsigned char* __restrict__ out8,
    float* __restrict__ out32, int nrows) {
    __shared__ uint4 atile[4][16][16];  // [wave][node][octet^node] 16 KB
    __shared__ float colp[2 * DIM];     // 1 KB

    const int tid = threadIdx.x;
    const int lane = tid & 63;
    const int wave = tid >> 6;
    const int l15 = lane & 15;
    const int lhi = lane >> 4;
    const int e4 = lhi, c16 = l15;
    const int nbase = blockIdx.x * 64 + wave * 16;

    if (tid < DIM) {
        float s = gamma[tid] * rsqrtf(var[tid] + BN_EPS);
        colp[tid * 2] = s;
        colp[tid * 2 + 1] = (bias[tid] - mean[tid]) * s + beta[tid];
    }

#define PRIME4(S0, S1, S2, S3, base_, hi_)                                    \
    S0 = ((base_) < (hi_)) ? col[(base_)] : -1;                               \
    S1 = ((base_) + 4 < (hi_)) ? col[(base_) + 4] : -1;                       \
    S2 = ((base_) + 8 < (hi_)) ? col[(base_) + 8] : -1;                       \
    S3 = ((base_) + 12 < (hi_)) ? col[(base_) + 12] : -1;

#define CVT8ACC(v, m, Q0, Q1, Q2, Q3, Q4, Q5, Q6, Q7)                         \
    {                                                                         \
        f32x2 f01 = __builtin_amdgcn_cvt_pk_f32_fp8((v).x, false);            \
        f32x2 f23 = __builtin_amdgcn_cvt_pk_f32_fp8((v).x, true);             \
        f32x2 f45 = __builtin_amdgcn_cvt_pk_f32_fp8((v).y, false);            \
        f32x2 f67 = __builtin_amdgcn_cvt_pk_f32_fp8((v).y, true);             \
        Q0 = fmaf(f01.x, m, Q0); Q1 = fmaf(f01.y, m, Q1);                     \
        Q2 = fmaf(f23.x, m, Q2); Q3 = fmaf(f23.y, m, Q3);                     \
        Q4 = fmaf(f45.x, m, Q4); Q5 = fmaf(f45.y, m, Q5);                     \
        Q6 = fmaf(f67.x, m, Q6); Q7 = fmaf(f67.y, m, Q7);                     \
    }

#define RED2(q) q += __shfl_xor(q, 16); q += __shfl_xor(q, 32);

    // ---- phase 1: gather-aggregate, 2 nodes in flight ----
    for (int i = 0; i < 16; i += 2) {
        const int nA = nbase + i, nB = nbase + i + 1;
        float A0 = 0.f, A1 = 0.f, A2 = 0.f, A3 = 0.f,
              A4 = 0.f, A5 = 0.f, A6 = 0.f, A7 = 0.f;
        float B0 = 0.f, B1 = 0.f, B2 = 0.f, B3 = 0.f,
              B4 = 0.f, B5 = 0.f, B6 = 0.f, B7 = 0.f;
        int loA = 0, hiA = 0, loB = 0, hiB = 0;
        if (nA < nrows) { loA = rowptr[nA]; hiA = rowptr[nA + 1]; }
        if (nB < nrows) { loB = rowptr[nB]; hiB = rowptr[nB + 1]; }
        int sA0, sA1, sA2, sA3, sB0, sB1, sB2, sB3;
        PRIME4(sA0, sA1, sA2, sA3, loA + e4, hiA)
        PRIME4(sB0, sB1, sB2, sB3, loB + e4, hiB)
        for (int jA = loA, jB = loB; jA < hiA || jB < hiB; jA += 16, jB += 16) {
            uint2 vA0 = x8in[(size_t)(sA0 > 0 ? sA0 : 0) * 16 + c16];
            uint2 vA1 = x8in[(size_t)(sA1 > 0 ? sA1 : 0) * 16 + c16];
            uint2 vA2 = x8in[(size_t)(sA2 > 0 ? sA2 : 0) * 16 + c16];
            uint2 vA3 = x8in[(size_t)(sA3 > 0 ? sA3 : 0) * 16 + c16];
            uint2 vB0 = x8in[(size_t)(sB0 > 0 ? sB0 : 0) * 16 + c16];
            uint2 vB1 = x8in[(size_t)(sB1 > 0 ? sB1 : 0) * 16 + c16];
            uint2 vB2 = x8in[(size_t)(sB2 > 0 ? sB2 : 0) * 16 + c16];
            uint2 vB3 = x8in[(size_t)(sB3 > 0 ? sB3 : 0) * 16 + c16];
            float mA0 = sA0 >= 0 ? 1.f : 0.f, mA1 = sA1 >= 0 ? 1.f : 0.f;
            float mA2 = sA2 >= 0 ? 1.f : 0.f, mA3 = sA3 >= 0 ? 1.f : 0.f;
            float mB0 = sB0 >= 0 ? 1.f : 0.f, mB1 = sB1 >= 0 ? 1.f : 0.f;
            float mB2 = sB2 >= 0 ? 1.f : 0.f, mB3 = sB3 >= 0 ? 1.f : 0.f;
            PRIME4(sA0, sA1, sA2, sA3, jA + 16 + e4, hiA)
            PRIME4(sB0, sB1, sB2, sB3, jB + 16 + e4, hiB)
            CVT8ACC(vA0, mA0, A0, A1, A2, A3, A4, A5, A6, A7)
            CVT8ACC(vA1, mA1, A0, A1, A2, A3, A4, A5, A6, A7)
            CVT8ACC(vA2, mA2, A0, A1, A2, A3, A4, A5, A6, A7)
            CVT8ACC(vA3, mA3, A0, A1, A2, A3, A4, A5, A6, A7)
            CVT8ACC(vB0, mB0, B0, B1, B2, B3, B4, B5, B6, B7)
            CVT8ACC(vB1, mB1, B0, B1, B2, B3, B4, B5, B6, B7)
            CVT8ACC(vB2, mB2, B0, B1, B2, B3, B4, B5, B6, B7)
            CVT8ACC(vB3, mB3, B0, B1, B2, B3, B4, B5, B6, B7)
        }
        RED2(A0) RED2(A1) RED2(A2) RED2(A3) RED2(A4) RED2(A5) RED2(A6) RED2(A7)
        RED2(B0) RED2(B1) RED2(B2) RED2(B3) RED2(B4) RED2(B5) RED2(B6) RED2(B7)
        if (lane < 16) {
            float scA = (nA < nrows) ? inv_deg[nA] : 0.f;
            float scB = (nB < nrows) ? inv_deg[nB] : 0.f;
            uint4 oA, oB;
            oA.x = pack2(A0 * scA, A1 * scA);
            oA.y = pack2(A2 * scA, A3 * scA);
            oA.z = pack2(A4 * scA, A5 * scA);
            oA.w = pack2(A6 * scA, A7 * scA);
            oB.x = pack2(B0 * scB, B1 * scB);
            oB.y = pack2(B2 * scB, B3 * scB);
            oB.z = pack2(B4 * scB, B5 * scB);
            oB.w = pack2(B6 * scB, B7 * scB);
            atile[wave][i][c16 ^ i] = oA;
            atile[wave][i + 1][c16 ^ (i + 1)] = oB;
        }
    }
#undef PRIME4
#undef CVT8ACC
#undef RED2

    // ---- phase 2: dual GEMM ----
    const int gnode = nbase + l15;
    const int arow = gnode < nrows ? gnode : nrows - 1;
    bf16x8 af1[4];
#pragma unroll
    for (int k = 0; k < 4; ++k)
        af1[k] = *(const bf16x8*)(xb + (size_t)arow * DIM + k * 32 + lhi * 8);

    __syncthreads();  // colp ready (atile is wave-private)

    bf16x8 af0[4];
#pragma unroll
    for (int k = 0; k < 4; ++k)
        af0[k] = __builtin_bit_cast(bf16x8, atile[wave][l15][(k * 4 + lhi) ^ l15]);

    f32x4 acc[8];
#pragma unroll
    for (int ct = 0; ct < 8; ++ct) acc[ct] = (f32x4){0.f, 0.f, 0.f, 0.f};

#pragma unroll
    for (int k = 0; k < 4; ++k) {
        bf16x8 bw[8];
#pragma unroll
        for (int ct = 0; ct < 8; ++ct)
            bw[ct] = *(const bf16x8*)(Wl + ((size_t)(ct * 4 + k) * 64 + lane) * 8);
#pragma unroll
        for (int ct = 0; ct < 8; ++ct)
            acc[ct] = __builtin_amdgcn_mfma_f32_16x16x32_bf16(bw[ct], af0[k],
                                                              acc[ct], 0, 0, 0);
    }
#pragma unroll
    for (int k = 0; k < 4; ++k) {
        bf16x8 bw[8];
#pragma unroll
        for (int ct = 0; ct < 8; ++ct)
            bw[ct] = *(const bf16x8*)(Wr + ((size_t)(ct * 4 + k) * 64 + lane) * 8);
#pragma unroll
        for (int ct = 0; ct < 8; ++ct)
            acc[ct] = __builtin_amdgcn_mfma_f32_16x16x32_bf16(bw[ct], af1[k],
                                                              acc[ct], 0, 0, 0);
    }

    // ---- epilogue ----
    if (gnode < nrows) {
#pragma unroll
        for (int ct = 0; ct < 8; ++ct) {
            int c0 = ct * 16 + lhi * 4;
            float h[4];
#pragma unroll
            for (int j = 0; j < 4; ++j) {
                float2 p = *(const float2*)&colp[(c0 + j) * 2];
                h[j] = fmaxf(acc[ct][j] * p.x + p.y, 0.f);
            }
            size_t base = (size_t)gnode * DIM + c0;
            if (outb) {  // layers 0-2: residual add + bf16 + fp8 mirrors
                uint2 rv = *(const uint2*)(xb + base);
                h[0] += bf_e0(rv.x); h[1] += bf_e1(rv.x);
                h[2] += bf_e0(rv.y); h[3] += bf_e1(rv.y);
                uint2 o;
                o.x = pack2(h[0], h[1]);
                o.y = pack2(h[2], h[3]);
                *(uint2*)(outb + base) = o;
                int w = __builtin_amdgcn_cvt_pk_fp8_f32(h[0], h[1], 0, false);
                w = __builtin_amdgcn_cvt_pk_fp8_f32(h[2], h[3], w, true);
                *(unsigned int*)(out8 + base) = (unsigned int)w;
            }
            if (out32)
                *(float4*)(out32 + base) = make_float4(h[0], h[1], h[2], h[3]);
        }
    }
}

extern "C" void kernel_launch(void* const* d_in, const int* in_sizes, int n_in,
                              void* d_out, int out_size, void* d_ws, size_t ws_size,
                              hipStream_t stream) {
    const float* x_in = (const float*)d_in[0];
    const int* ei     = (const int*)d_in[1];
    const float* Wp   = (const float*)d_in[2];
    const float* bp   = (const float*)d_in[3];
    const float* Wl   = (const float*)d_in[4];
    const float* bl   = (const float*)d_in[5];
    const float* Wr   = (const float*)d_in[6];
    const float* g    = (const float*)d_in[7];
    const float* be   = (const float*)d_in[8];
    const float* mu   = (const float*)d_in[9];
    const float* va   = (const float*)d_in[10];

    const int N = in_sizes[0] / DIM;
    const int E = in_sizes[1] / 2;
    const int* src = ei;
    const int* dst = ei + E;
    const int NB = (N + 255) >> 8;  // buckets of 256 nodes

    // ---- workspace carve (256B aligned) ----
    char* p = (char*)d_ws;
    auto alloc = [&](size_t bytes) {
        char* r = p;
        p += (bytes + 255) & ~(size_t)255;
        return r;
    };
    float* inv_deg = (float*)alloc((size_t)N * 4);
    int* rowptr    = (int*)alloc((size_t)(N + 1) * 4);
    int* cursor    = (int*)alloc((size_t)NB * 4);
    int* col       = (int*)alloc((size_t)E * 4);
    unsigned int* binned = (unsigned int*)alloc((size_t)NB * BCAP * 4);
    unsigned short* xb   = (unsigned short*)alloc((size_t)N * DIM * 2);
    unsigned char* x8a   = (unsigned char*)alloc((size_t)N * DIM);
    unsigned char* x8b   = (unsigned char*)alloc((size_t)N * DIM);
    unsigned short* WTf  = (unsigned short*)alloc((size_t)9 * 16384 * 2);

    // ---- CSR build (k_bin also transforms weights in tail blocks) ----
    hipMemsetAsync(cursor, 0, (size_t)NB * 4, stream);
    k_bin<<<(E + EPB - 1) / EPB, 256, 0, stream>>>(src, dst, cursor, binned,
                                                   Wp, Wl, Wr, WTf, E, NB);
    k_csr<<<NB, 256, 0, stream>>>(cursor, binned, rowptr, inv_deg, col, N, NB);

    const int gblocks = (N + 63) / 64;

    // ---- projection: x = relu(x_in @ Wp + bp) -> xb (bf16) + x8a (fp8) ----
    k_proj<<<gblocks, 256, 0, stream>>>(x_in, WTf, bp, xb, x8a, N);

    float* out = (float*)d_out;
    unsigned char* x8rd = x8a;
    unsigned char* x8wr = x8b;
    for (int i = 0; i < 4; ++i) {
        const unsigned short* WlF = WTf + (size_t)(1 + i) * 16384;
        const unsigned short* WrF = WTf + (size_t)(5 + i) * 16384;
        const bool last = (i == 3);
        k_layer<<<gblocks, 256, 0, stream>>>(
            (const uint2*)x8rd, xb, rowptr, col, inv_deg, WlF, WrF,
            bl + i * DIM, g + i * DIM, be + i * DIM, mu + i * DIM, va + i * DIM,
            last ? nullptr : xb, last ? nullptr : x8wr,
            last ? out : nullptr, N);
        unsigned char* t = x8rd; x8rd = x8wr; x8wr = t;
    }
}

// Round 14
// 225.459 us; speedup vs baseline: 1.4119x; 1.4119x over previous
//
#include <hip/hip_runtime.h>

#define DIM 128
#define BN_EPS 1e-5f
#define BSH 6            // 64-node buckets
#define BCAP 2048        // per-bucket capacity (mean ~1024 for E=800k, NB=782)
#define EPB 1024         // edges per k_bin block
#define EPT 4            // edges per thread in k_bin
#define MAXNB 1024       // LDS array bound (N <= 65536)

typedef __bf16 bf16x8 __attribute__((ext_vector_type(8)));
typedef float f32x4 __attribute__((ext_vector_type(4)));
typedef float f32x2 __attribute__((ext_vector_type(2)));

__device__ __forceinline__ float bf_e0(unsigned int u) {
    return __builtin_bit_cast(float, u << 16);
}
__device__ __forceinline__ float bf_e1(unsigned int u) {
    return __builtin_bit_cast(float, u & 0xffff0000u);
}
__device__ __forceinline__ unsigned short f2b(float f) {
    __bf16 b = (__bf16)f;  // RTN hardware convert
    return __builtin_bit_cast(unsigned short, b);
}
__device__ __forceinline__ unsigned int pack2(float lo, float hi) {
    return (unsigned int)f2b(lo) | ((unsigned int)f2b(hi) << 16);
}

// async global->LDS, 16B per lane: lds base is wave-uniform, gsrc per-lane.
#define GLOAD_LDS16(gsrc, ldst)                                               \
    __builtin_amdgcn_global_load_lds(                                         \
        (const __attribute__((address_space(1))) void*)(gsrc),                \
        (__attribute__((address_space(3))) void*)(ldst), 16, 0, 0)

// ---------------- pass 1: bin edges by dst>>6 + weight transform tail -------
// entry: (dst&63)<<17 | src   (requires N <= 2^17)
__global__ __launch_bounds__(256) void k_bin(const int* __restrict__ src,
                                             const int* __restrict__ dst,
                                             int* __restrict__ cursor,
                                             unsigned int* __restrict__ binned,
                                             const float* __restrict__ Wp,
                                             const float* __restrict__ Wl,
                                             const float* __restrict__ Wr,
                                             unsigned short* __restrict__ WTf,
                                             int E, int NB) {
    __shared__ int hist[MAXNB];
    __shared__ int base[MAXNB];
    __shared__ int c2[MAXNB];
    const int tid = threadIdx.x;
    const int e0 = blockIdx.x * EPB;

    unsigned int u[EPT];
    int b[EPT];
    for (int j = tid; j < MAXNB; j += 256) {
        hist[j] = 0;
        c2[j] = 0;
    }
    __syncthreads();
#pragma unroll
    for (int i = 0; i < EPT; ++i) {
        int e = e0 + i * 256 + tid;
        if (e < E) {
            int d = dst[e];
            b[i] = d >> BSH;
            u[i] = ((unsigned int)(d & 63) << 17) | (unsigned int)src[e];
            atomicAdd(&hist[b[i]], 1);
        } else {
            b[i] = -1;
        }
    }
    __syncthreads();
    for (int j = tid; j < NB; j += 256)
        if (hist[j] > 0) base[j] = atomicAdd(&cursor[j], hist[j]);
    __syncthreads();
#pragma unroll
    for (int i = 0; i < EPT; ++i) {
        if (b[i] < 0) continue;
        int p = base[b[i]] + atomicAdd(&c2[b[i]], 1);
        if (p < BCAP) binned[(size_t)b[i] * BCAP + p] = u[i];
    }

    // ---- tail: weights -> bf16 FRAGMENT-MAJOR (first 72 blocks) ----
    // WTf[m]: frag (ct,k,lane) at ((ct*4+k)*64+lane)*8 holding
    // W^T[ct*16+(lane&15)][k*32+(lane>>4)*8+e], e=0..7 (A-operand layout).
    int gid = blockIdx.x * 256 + tid;
    if (gid < 9 * 2048) {
        int m = gid >> 11;
        int r = gid & 2047;
        int lane = r & 63;
        int k = (r >> 6) & 3;
        int ct = r >> 8;
        int feat = ct * 16 + (lane & 15);
        int kb = k * 32 + (lane >> 4) * 8;
        const float* W = (m == 0) ? Wp : (m < 5) ? (Wl + (size_t)(m - 1) * DIM * DIM)
                                                 : (Wr + (size_t)(m - 5) * DIM * DIM);
        unsigned short o[8];
#pragma unroll
        for (int e = 0; e < 8; ++e) o[e] = f2b(W[(size_t)(kb + e) * DIM + feat]);
        *(uint4*)(WTf + (size_t)gid * 8) = *(const uint4*)o;
    }
}

// ---------------- pass 2: per-bucket CSR (64 nodes/bucket, grid = NB) -------
__global__ __launch_bounds__(256) void k_csr(const int* __restrict__ cursor,
                                             const unsigned int* __restrict__ binned,
                                             int* __restrict__ rowptr,
                                             float* __restrict__ inv_deg,
                                             int* __restrict__ col, int N, int NB) {
    __shared__ unsigned int stage[BCAP];   // 8 KB
    __shared__ int deg[64];
    __shared__ int startsh[64];
    __shared__ int red[256];
    const int b = blockIdx.x;
    const int t = threadIdx.x;
    const int node0 = b << BSH;
    const int cnt = min(cursor[b], BCAP);

    // ---- gbase = sum_{j<b} min(cursor[j],BCAP) : 256-thread reduction ----
    int part = 0;
    for (int j = t; j < b; j += 256) part += min(cursor[j], BCAP);
    red[t] = part;
    if (t < 64) deg[t] = 0;
    __syncthreads();
    for (int off = 128; off > 0; off >>= 1) {
        if (t < off) red[t] += red[t + off];
        __syncthreads();
    }
    const int gbase = red[0];

    // ---- stage + histogram ----
    for (int e = t; e < cnt; e += 256) {
        unsigned int u = binned[(size_t)b * BCAP + e];
        stage[e] = u;
        atomicAdd(&deg[u >> 17], 1);
    }
    __syncthreads();
    // ---- inclusive scan over 64 degs ----
    if (t < 64) startsh[t] = deg[t];
    __syncthreads();
    for (int off = 1; off < 64; off <<= 1) {
        int a = (t >= off && t < 64) ? startsh[t - off] : 0;
        __syncthreads();
        if (t < 64) startsh[t] += a;
        __syncthreads();
    }
    int ex = 0, dd = 0;
    if (t < 64) {
        dd = deg[t];
        ex = startsh[t] - dd;
    }
    __syncthreads();
    if (t < 64) {
        deg[t] = ex;  // running cursor for scatter
        int node = node0 + t;
        if (node < N) {
            rowptr[node] = gbase + ex;
            inv_deg[node] = 1.0f / (float)(dd > 1 ? dd : 1);
        }
    }
    if (b == NB - 1 && t == 0) rowptr[N] = gbase + cnt;
    __syncthreads();
    // ---- scatter (contiguous ~8KB range -> XCD-local) ----
    for (int e = t; e < cnt; e += 256) {
        unsigned int u = stage[e];
        int dl = u >> 17;
        int p = atomicAdd(&deg[dl], 1);
        col[gbase + p] = (int)(u & 0x1ffffu);
    }
}

// ---------------- projection GEMM: x = relu(x_in @ Wp + bp) -> bf16 + fp8 ----
__global__ __launch_bounds__(256) void k_proj(
    const float* __restrict__ Ain, const unsigned short* __restrict__ Wf,
    const float* __restrict__ bias,
    unsigned short* __restrict__ outb, unsigned char* __restrict__ out8,
    int nrows) {
    __shared__ unsigned short wlds[16384];  // 32 KB

    const int tid = threadIdx.x;
    const int lane = tid & 63;
    const int l15 = lane & 15;
    const int lhi = lane >> 4;
    const int wave = tid >> 6;
    const int node = blockIdx.x * 64 + wave * 16 + l15;
    const int arow = node < nrows ? node : nrows - 1;

    bf16x8 af[4];
    {
        const float* a0 = Ain + (size_t)arow * DIM + lhi * 8;
#pragma unroll
        for (int k = 0; k < 4; ++k) {
            float4 v0 = *(const float4*)(a0 + k * 32);
            float4 v1 = *(const float4*)(a0 + k * 32 + 4);
            bf16x8 f;
            f[0] = (__bf16)v0.x; f[1] = (__bf16)v0.y;
            f[2] = (__bf16)v0.z; f[3] = (__bf16)v0.w;
            f[4] = (__bf16)v1.x; f[5] = (__bf16)v1.y;
            f[6] = (__bf16)v1.z; f[7] = (__bf16)v1.w;
            af[k] = f;
        }
    }
    {
        const unsigned short* g = Wf + (size_t)wave * 4096 + lane * 8;
#pragma unroll
        for (int i = 0; i < 8; ++i)
            GLOAD_LDS16(g + i * 512, &wlds[wave * 4096 + i * 512]);
    }

    f32x4 acc[8];
#pragma unroll
    for (int ct = 0; ct < 8; ++ct) acc[ct] = (f32x4){0.f, 0.f, 0.f, 0.f};

    __syncthreads();

#pragma unroll
    for (int k = 0; k < 4; ++k) {
        bf16x8 bw[8];
#pragma unroll
        for (int ct = 0; ct < 8; ++ct)
            bw[ct] = *(const bf16x8*)&wlds[((ct * 4 + k) * 64 + lane) * 8];
#pragma unroll
        for (int ct = 0; ct < 8; ++ct)
            acc[ct] = __builtin_amdgcn_mfma_f32_16x16x32_bf16(bw[ct], af[k],
                                                              acc[ct], 0, 0, 0);
    }

    if (node < nrows) {
#pragma unroll
        for (int ct = 0; ct < 8; ++ct) {
            int c0 = ct * 16 + lhi * 4;
            float4 bb = *(const float4*)(bias + c0);
            float h[4];
            h[0] = fmaxf(acc[ct][0] + bb.x, 0.f);
            h[1] = fmaxf(acc[ct][1] + bb.y, 0.f);
            h[2] = fmaxf(acc[ct][2] + bb.z, 0.f);
            h[3] = fmaxf(acc[ct][3] + bb.w, 0.f);
            size_t base = (size_t)node * DIM + c0;
            uint2 o;
            o.x = pack2(h[0], h[1]);
            o.y = pack2(h[2], h[3]);
            *(uint2*)(outb + base) = o;
            int w = __builtin_amdgcn_cvt_pk_fp8_f32(h[0], h[1], 0, false);
            w = __builtin_amdgcn_cvt_pk_fp8_f32(h[2], h[3], w, true);
            *(unsigned int*)(out8 + base) = (unsigned int)w;
        }
    }
}

// ---------------- mean aggregation: fp8 table, 4x16 4-deep pipeline (R10) ----
// x8: fp8 e4m3, row-major [node][128]. lane (e4,c16): 4 edge-groups x
// 16 feat-lanes; uint2 = 8 fp8 feats at c16*8. Unroll x4: 16 rows in flight.
__global__ void k_agg(const uint2* __restrict__ x8_2, const int* __restrict__ rowptr,
                      const int* __restrict__ col, const float* __restrict__ inv_deg,
                      uint4* __restrict__ aggb4, int n) {
    int node = (blockIdx.x * blockDim.x + threadIdx.x) >> 6;
    int lane = threadIdx.x & 63;
    if (node >= n) return;
    const int e4 = lane >> 4, c16 = lane & 15;
    const int lo = rowptr[node], hi = rowptr[node + 1];

    float a0 = 0.f, a1 = 0.f, a2 = 0.f, a3 = 0.f,
          a4 = 0.f, a5 = 0.f, a6 = 0.f, a7 = 0.f;

    int i0 = lo + e4;
    int s0 = (i0      < hi) ? col[i0]      : -1;
    int s1 = (i0 + 4  < hi) ? col[i0 + 4]  : -1;
    int s2 = (i0 + 8  < hi) ? col[i0 + 8]  : -1;
    int s3 = (i0 + 12 < hi) ? col[i0 + 12] : -1;

    for (int j = lo; j < hi; j += 16) {
        uint2 v0 = x8_2[(size_t)(s0 > 0 ? s0 : 0) * 16 + c16];
        uint2 v1 = x8_2[(size_t)(s1 > 0 ? s1 : 0) * 16 + c16];
        uint2 v2 = x8_2[(size_t)(s2 > 0 ? s2 : 0) * 16 + c16];
        uint2 v3 = x8_2[(size_t)(s3 > 0 ? s3 : 0) * 16 + c16];
        float m0 = s0 >= 0 ? 1.f : 0.f;
        float m1 = s1 >= 0 ? 1.f : 0.f;
        float m2 = s2 >= 0 ? 1.f : 0.f;
        float m3 = s3 >= 0 ? 1.f : 0.f;
        int nj = j + 16 + e4;
        s0 = (nj      < hi) ? col[nj]      : -1;
        s1 = (nj + 4  < hi) ? col[nj + 4]  : -1;
        s2 = (nj + 8  < hi) ? col[nj + 8]  : -1;
        s3 = (nj + 12 < hi) ? col[nj + 12] : -1;
#define ACC_(v, m)                                                            \
        {                                                                     \
            f32x2 f01 = __builtin_amdgcn_cvt_pk_f32_fp8(v.x, false);          \
            f32x2 f23 = __builtin_amdgcn_cvt_pk_f32_fp8(v.x, true);           \
            f32x2 f45 = __builtin_amdgcn_cvt_pk_f32_fp8(v.y, false);          \
            f32x2 f67 = __builtin_amdgcn_cvt_pk_f32_fp8(v.y, true);           \
            a0 = fmaf(f01.x, m, a0); a1 = fmaf(f01.y, m, a1);                 \
            a2 = fmaf(f23.x, m, a2); a3 = fmaf(f23.y, m, a3);                 \
            a4 = fmaf(f45.x, m, a4); a5 = fmaf(f45.y, m, a5);                 \
            a6 = fmaf(f67.x, m, a6); a7 = fmaf(f67.y, m, a7);                 \
        }
        ACC_(v0, m0) ACC_(v1, m1) ACC_(v2, m2) ACC_(v3, m3)
#undef ACC_
    }
#define RED_(a) a += __shfl_xor(a, 16); a += __shfl_xor(a, 32);
    RED_(a0) RED_(a1) RED_(a2) RED_(a3) RED_(a4) RED_(a5) RED_(a6) RED_(a7)
#undef RED_
    float sc = inv_deg[node];
    uint4 o;
    o.x = pack2(a0 * sc, a1 * sc);
    o.y = pack2(a2 * sc, a3 * sc);
    o.z = pack2(a4 * sc, a5 * sc);
    o.w = pack2(a6 * sc, a7 * sc);
    if (lane < 16) aggb4[(size_t)node * 16 + c16] = o;
}

// ---------------- MFMA dual-GEMM: async W staging + hoisted A loads ----------
// block = 256 thr = 4 waves; wave = 16 nodes x 128 feats; grid = N/64.
__global__ __launch_bounds__(256) void k_gemm(
    const unsigned short* __restrict__ A0, const unsigned short* __restrict__ A1,
    const unsigned short* __restrict__ Wf0, const unsigned short* __restrict__ Wf1,
    const float* __restrict__ bias,
    const float* __restrict__ gamma, const float* __restrict__ beta,
    const float* __restrict__ mean, const float* __restrict__ var,
    const unsigned short* __restrict__ residb,
    float* __restrict__ out32, unsigned short* __restrict__ outb,
    unsigned char* __restrict__ out8, int nrows) {
    __shared__ unsigned short wlds[16384];  // 32 KB: one segment's frags
    __shared__ float colp[2 * DIM];         // per-col (scale, shift)

    const int tid = threadIdx.x;
    const int lane = tid & 63;
    const int l15 = lane & 15;
    const int lhi = lane >> 4;
    const int wave = tid >> 6;
    const int node = blockIdx.x * 64 + wave * 16 + l15;
    const int arow = node < nrows ? node : nrows - 1;  // clamped read row

    // ---- issue A0 fragment loads first (latency under staging+barrier) ----
    bf16x8 af0[4];
    {
        const unsigned short* a0 = A0 + (size_t)arow * DIM + lhi * 8;
#pragma unroll
        for (int k = 0; k < 4; ++k) af0[k] = *(const bf16x8*)(a0 + k * 32);
    }

    // ---- stage seg0 W frags: async DMA, 8 x 1KB per wave, linear ----
    {
        const unsigned short* g = Wf0 + (size_t)wave * 4096 + lane * 8;
#pragma unroll
        for (int i = 0; i < 8; ++i)
            GLOAD_LDS16(g + i * 512, &wlds[wave * 4096 + i * 512]);
    }

    if (tid < DIM) {
        float s = gamma[tid] * rsqrtf(var[tid] + BN_EPS);
        colp[tid * 2] = s;
        colp[tid * 2 + 1] = (bias[tid] - mean[tid]) * s + beta[tid];
    }

    f32x4 acc[8];
#pragma unroll
    for (int ct = 0; ct < 8; ++ct) acc[ct] = (f32x4){0.f, 0.f, 0.f, 0.f};

    __syncthreads();  // W0 in LDS (barrier drains vmcnt)

    // ---- issue A1 loads now: latency hides under seg0 MFMAs ----
    bf16x8 af1[4];
    {
        const unsigned short* a1 = A1 + (size_t)arow * DIM + lhi * 8;
#pragma unroll
        for (int k = 0; k < 4; ++k) af1[k] = *(const bf16x8*)(a1 + k * 32);
    }

    // ---- seg0 compute ----
#pragma unroll
    for (int k = 0; k < 4; ++k) {
        bf16x8 bw[8];
#pragma unroll
        for (int ct = 0; ct < 8; ++ct)
            bw[ct] = *(const bf16x8*)&wlds[((ct * 4 + k) * 64 + lane) * 8];
#pragma unroll
        for (int ct = 0; ct < 8; ++ct)
            acc[ct] = __builtin_amdgcn_mfma_f32_16x16x32_bf16(bw[ct], af0[k],
                                                              acc[ct], 0, 0, 0);
    }

    __syncthreads();  // all waves done reading W0
    {
        const unsigned short* g = Wf1 + (size_t)wave * 4096 + lane * 8;
#pragma unroll
        for (int i = 0; i < 8; ++i)
            GLOAD_LDS16(g + i * 512, &wlds[wave * 4096 + i * 512]);
    }
    __syncthreads();  // W1 in LDS
#pragma unroll
    for (int k = 0; k < 4; ++k) {
        bf16x8 bw[8];
#pragma unroll
        for (int ct = 0; ct < 8; ++ct)
            bw[ct] = *(const bf16x8*)&wlds[((ct * 4 + k) * 64 + lane) * 8];
#pragma unroll
        for (int ct = 0; ct < 8; ++ct)
            acc[ct] = __builtin_amdgcn_mfma_f32_16x16x32_bf16(bw[ct], af1[k],
                                                              acc[ct], 0, 0, 0);
    }

    // ---- epilogue: thread owns feats ct*16+lhi*4..+3 of node ----
    if (node < nrows) {
#pragma unroll
        for (int ct = 0; ct < 8; ++ct) {
            int c0 = ct * 16 + lhi * 4;
            float h[4];
#pragma unroll
            for (int j = 0; j < 4; ++j) {
                float2 p = *(const float2*)&colp[(c0 + j) * 2];
                h[j] = fmaxf(acc[ct][j] * p.x + p.y, 0.f);
            }
            size_t base = (size_t)node * DIM + c0;
            if (residb) {
                uint2 rv = *(const uint2*)(residb + base);
                h[0] += bf_e0(rv.x); h[1] += bf_e1(rv.x);
                h[2] += bf_e0(rv.y); h[3] += bf_e1(rv.y);
            }
            if (outb) {
                uint2 o;
                o.x = pack2(h[0], h[1]);
                o.y = pack2(h[2], h[3]);
                *(uint2*)(outb + base) = o;
            }
            if (out8) {
                int w = __builtin_amdgcn_cvt_pk_fp8_f32(h[0], h[1], 0, false);
                w = __builtin_amdgcn_cvt_pk_fp8_f32(h[2], h[3], w, true);
                *(unsigned int*)(out8 + base) = (unsigned int)w;
            }
            if (out32)
                *(float4*)(out32 + base) = make_float4(h[0], h[1], h[2], h[3]);
        }
    }
}

extern "C" void kernel_launch(void* const* d_in, const int* in_sizes, int n_in,
                              void* d_out, int out_size, void* d_ws, size_t ws_size,
                              hipStream_t stream) {
    const float* x_in = (const float*)d_in[0];
    const int* ei     = (const int*)d_in[1];
    const float* Wp   = (const float*)d_in[2];
    const float* bp   = (const float*)d_in[3];
    const float* Wl   = (const float*)d_in[4];
    const float* bl   = (const float*)d_in[5];
    const float* Wr   = (const float*)d_in[6];
    const float* g    = (const float*)d_in[7];
    const float* be   = (const float*)d_in[8];
    const float* mu   = (const float*)d_in[9];
    const float* va   = (const float*)d_in[10];

    const int N = in_sizes[0] / DIM;
    const int E = in_sizes[1] / 2;
    const int* src = ei;
    const int* dst = ei + E;
    const int NB = (N + 63) >> BSH;  // 64-node buckets

    // ---- workspace carve (256B aligned) ----
    char* p = (char*)d_ws;
    auto alloc = [&](size_t bytes) {
        char* r = p;
        p += (bytes + 255) & ~(size_t)255;
        return r;
    };
    float* inv_deg = (float*)alloc((size_t)N * 4);
    int* rowptr    = (int*)alloc((size_t)(N + 1) * 4);
    int* cursor    = (int*)alloc((size_t)NB * 4);
    int* col       = (int*)alloc((size_t)E * 4);
    unsigned int* binned = (unsigned int*)alloc((size_t)NB * BCAP * 4);
    unsigned short* xb   = (unsigned short*)alloc((size_t)N * DIM * 2);
    unsigned char* x8    = (unsigned char*)alloc((size_t)N * DIM);
    unsigned short* aggb = (unsigned short*)alloc((size_t)N * DIM * 2);
    unsigned short* WTf  = (unsigned short*)alloc((size_t)9 * 16384 * 2);

    // ---- CSR build (k_bin also transforms weights in tail blocks) ----
    hipMemsetAsync(cursor, 0, (size_t)NB * 4, stream);
    k_bin<<<(E + EPB - 1) / EPB, 256, 0, stream>>>(src, dst, cursor, binned,
                                                   Wp, Wl, Wr, WTf, E, NB);
    k_csr<<<NB, 256, 0, stream>>>(cursor, binned, rowptr, inv_deg, col, N, NB);

    const int gblocks = (N + 63) / 64;

    // ---- projection: x = relu(x_in @ Wp + bp) -> xb (bf16) + x8 (fp8) ----
    k_proj<<<gblocks, 256, 0, stream>>>(x_in, WTf, bp, xb, x8, N);

    float* out = (float*)d_out;
    for (int i = 0; i < 4; ++i) {
        k_agg<<<(N + 3) / 4, 256, 0, stream>>>((const uint2*)x8, rowptr, col,
                                               inv_deg, (uint4*)aggb, N);
        const unsigned short* WlF = WTf + (size_t)(1 + i) * 16384;
        const unsigned short* WrF = WTf + (size_t)(5 + i) * 16384;
        // layers 0..2: xb/x8 = bf16/fp8(xb + relu(bn(h)));  layer 3: out fp32
        k_gemm<<<gblocks, 256, 0, stream>>>(
            aggb, xb, WlF, WrF, bl + i * DIM,
            g + i * DIM, be + i * DIM, mu + i * DIM, va + i * DIM,
            (i < 3) ? xb : nullptr,
            (i < 3) ? nullptr : out, (i < 3) ? xb : nullptr,
            (i < 3) ? x8 : nullptr, N);
    }
}

// Round 15
// 201.900 us; speedup vs baseline: 1.5767x; 1.1167x over previous
//
#include <hip/hip_runtime.h>

#define DIM 128
#define BN_EPS 1e-5f
#define BCAP 8192        // per-bucket capacity (mean ~4082 for E=800k, NB=196)
#define EPB 4096         // edges per k_bin block
#define EPT 16           // edges per thread in k_bin

typedef __bf16 bf16x8 __attribute__((ext_vector_type(8)));
typedef float f32x4 __attribute__((ext_vector_type(4)));
typedef float f32x2 __attribute__((ext_vector_type(2)));

__device__ __forceinline__ float bf_e0(unsigned int u) {
    return __builtin_bit_cast(float, u << 16);
}
__device__ __forceinline__ float bf_e1(unsigned int u) {
    return __builtin_bit_cast(float, u & 0xffff0000u);
}
__device__ __forceinline__ unsigned short f2b(float f) {
    __bf16 b = (__bf16)f;  // RTN hardware convert
    return __builtin_bit_cast(unsigned short, b);
}
__device__ __forceinline__ unsigned int pack2(float lo, float hi) {
    return (unsigned int)f2b(lo) | ((unsigned int)f2b(hi) << 16);
}

// async global->LDS, 16B per lane: lds base is wave-uniform, gsrc per-lane.
#define GLOAD_LDS16(gsrc, ldst)                                               \
    __builtin_amdgcn_global_load_lds(                                         \
        (const __attribute__((address_space(1))) void*)(gsrc),                \
        (__attribute__((address_space(3))) void*)(ldst), 16, 0, 0)

// ---------------- pass 1: bin edges by dst>>8 + weight transform tail -------
// entry: (dst&255)<<17 | src   (requires N <= 2^17)
__global__ __launch_bounds__(256) void k_bin(const int* __restrict__ src,
                                             const int* __restrict__ dst,
                                             int* __restrict__ cursor,
                                             unsigned int* __restrict__ binned,
                                             const float* __restrict__ Wp,
                                             const float* __restrict__ Wl,
                                             const float* __restrict__ Wr,
                                             unsigned short* __restrict__ WTf,
                                             int E, int NB) {
    __shared__ int hist[256];
    __shared__ int base[256];
    __shared__ int c2[256];
    const int tid = threadIdx.x;
    const int e0 = blockIdx.x * EPB;

    unsigned int u[EPT];
    int b[EPT];
    hist[tid] = 0;
    c2[tid] = 0;
    __syncthreads();
#pragma unroll
    for (int i = 0; i < EPT; ++i) {
        int e = e0 + i * 256 + tid;
        if (e < E) {
            int d = dst[e];
            b[i] = d >> 8;
            u[i] = ((unsigned int)(d & 255) << 17) | (unsigned int)src[e];
            atomicAdd(&hist[b[i]], 1);
        } else {
            b[i] = -1;
        }
    }
    __syncthreads();
    if (tid < NB && hist[tid] > 0) base[tid] = atomicAdd(&cursor[tid], hist[tid]);
    __syncthreads();
#pragma unroll
    for (int i = 0; i < EPT; ++i) {
        if (b[i] < 0) continue;
        int p = base[b[i]] + atomicAdd(&c2[b[i]], 1);
        if (p < BCAP) binned[(size_t)b[i] * BCAP + p] = u[i];
    }

    // ---- tail: weights -> bf16 FRAGMENT-MAJOR (first 72 blocks) ----
    // WTf[m]: frag (ct,k,lane) at ((ct*4+k)*64+lane)*8 holding
    // W^T[ct*16+(lane&15)][k*32+(lane>>4)*8+e], e=0..7 (A-operand layout).
    int gid = blockIdx.x * 256 + tid;
    if (gid < 9 * 2048) {
        int m = gid >> 11;
        int r = gid & 2047;
        int lane = r & 63;
        int k = (r >> 6) & 3;
        int ct = r >> 8;
        int feat = ct * 16 + (lane & 15);
        int kb = k * 32 + (lane >> 4) * 8;
        const float* W = (m == 0) ? Wp : (m < 5) ? (Wl + (size_t)(m - 1) * DIM * DIM)
                                                 : (Wr + (size_t)(m - 5) * DIM * DIM);
        unsigned short o[8];
#pragma unroll
        for (int e = 0; e < 8; ++e) o[e] = f2b(W[(size_t)(kb + e) * DIM + feat]);
        *(uint4*)(WTf + (size_t)gid * 8) = *(const uint4*)o;
    }
}

// ---------------- pass 2 MERGED: blocks [0,NB) build CSR; rest do proj GEMM --
// CSR part: per-bucket (256 nodes) deg/rowptr/inv_deg/col, R12 structure.
// Proj part: x = relu(x_in @ Wp + bp) -> xb (bf16) + x8 (fp8); fills the CUs
// that would idle under the 196-block latency-bound CSR phase.
__global__ __launch_bounds__(256) void k_csr_proj(
    const int* __restrict__ cursor, const unsigned int* __restrict__ binned,
    int* __restrict__ rowptr, float* __restrict__ inv_deg,
    int* __restrict__ col, int N, int NB,
    const float* __restrict__ Ain, const unsigned short* __restrict__ Wf,
    const float* __restrict__ bias,
    unsigned short* __restrict__ outb, unsigned char* __restrict__ out8) {
    __shared__ unsigned int smem[BCAP + 768];  // 35 KB, shared by both paths
    const int t = threadIdx.x;

    if (blockIdx.x < NB) {
        // ================= CSR path =================
        unsigned int* stage = smem;                 // [BCAP]
        int* deg   = (int*)&smem[BCAP];             // [256]
        int* start = (int*)&smem[BCAP + 256];       // [256]
        int* sh    = (int*)&smem[BCAP + 512];       // [256]
        const int b = blockIdx.x;
        const int node0 = b << 8;

        int v = (t < NB) ? min(cursor[t], BCAP) : 0;
        sh[t] = v;
        deg[t] = 0;
        __syncthreads();
        for (int off = 1; off < 256; off <<= 1) {
            int a = (t >= off) ? sh[t - off] : 0;
            __syncthreads();
            sh[t] += a;
            __syncthreads();
        }
        const int gbase = sh[b] - min(cursor[b], BCAP);
        const int cnt = min(cursor[b], BCAP);
        if (b == 0 && t == 255) rowptr[N] = sh[255];

        for (int e = t; e < cnt; e += 256) {
            unsigned int u = binned[(size_t)b * BCAP + e];
            stage[e] = u;
            atomicAdd(&deg[u >> 17], 1);
        }
        __syncthreads();
        int d = deg[t];
        start[t] = d;
        __syncthreads();
        for (int off = 1; off < 256; off <<= 1) {
            int a = (t >= off) ? start[t - off] : 0;
            __syncthreads();
            start[t] += a;
            __syncthreads();
        }
        int excl = start[t] - d;
        int node = node0 + t;
        if (node < N) {
            rowptr[node] = gbase + excl;
            inv_deg[node] = 1.0f / (float)(d > 1 ? d : 1);
        }
        __syncthreads();
        deg[t] = excl;  // reuse as running cursor
        __syncthreads();
        for (int e = t; e < cnt; e += 256) {
            unsigned int u = stage[e];
            int dl = u >> 17;
            int p = atomicAdd(&deg[dl], 1);
            col[gbase + p] = (int)(u & 0x1ffffu);
        }
    } else {
        // ================= projection GEMM path =================
        unsigned short* wlds = (unsigned short*)smem;  // 32 KB
        const int lane = t & 63;
        const int l15 = lane & 15;
        const int lhi = lane >> 4;
        const int wave = t >> 6;
        const int node = (blockIdx.x - NB) * 64 + wave * 16 + l15;
        const int arow = node < N ? node : N - 1;

        bf16x8 af[4];
        {
            const float* a0 = Ain + (size_t)arow * DIM + lhi * 8;
#pragma unroll
            for (int k = 0; k < 4; ++k) {
                float4 v0 = *(const float4*)(a0 + k * 32);
                float4 v1 = *(const float4*)(a0 + k * 32 + 4);
                bf16x8 f;
                f[0] = (__bf16)v0.x; f[1] = (__bf16)v0.y;
                f[2] = (__bf16)v0.z; f[3] = (__bf16)v0.w;
                f[4] = (__bf16)v1.x; f[5] = (__bf16)v1.y;
                f[6] = (__bf16)v1.z; f[7] = (__bf16)v1.w;
                af[k] = f;
            }
        }
        {
            const unsigned short* g = Wf + (size_t)wave * 4096 + lane * 8;
#pragma unroll
            for (int i = 0; i < 8; ++i)
                GLOAD_LDS16(g + i * 512, &wlds[wave * 4096 + i * 512]);
        }

        f32x4 acc[8];
#pragma unroll
        for (int ct = 0; ct < 8; ++ct) acc[ct] = (f32x4){0.f, 0.f, 0.f, 0.f};

        __syncthreads();

#pragma unroll
        for (int k = 0; k < 4; ++k) {
            bf16x8 bw[8];
#pragma unroll
            for (int ct = 0; ct < 8; ++ct)
                bw[ct] = *(const bf16x8*)&wlds[((ct * 4 + k) * 64 + lane) * 8];
#pragma unroll
            for (int ct = 0; ct < 8; ++ct)
                acc[ct] = __builtin_amdgcn_mfma_f32_16x16x32_bf16(bw[ct], af[k],
                                                                  acc[ct], 0, 0, 0);
        }

        if (node < N) {
#pragma unroll
            for (int ct = 0; ct < 8; ++ct) {
                int c0 = ct * 16 + lhi * 4;
                float4 bb = *(const float4*)(bias + c0);
                float h[4];
                h[0] = fmaxf(acc[ct][0] + bb.x, 0.f);
                h[1] = fmaxf(acc[ct][1] + bb.y, 0.f);
                h[2] = fmaxf(acc[ct][2] + bb.z, 0.f);
                h[3] = fmaxf(acc[ct][3] + bb.w, 0.f);
                size_t base = (size_t)node * DIM + c0;
                uint2 o;
                o.x = pack2(h[0], h[1]);
                o.y = pack2(h[2], h[3]);
                *(uint2*)(outb + base) = o;
                int w = __builtin_amdgcn_cvt_pk_fp8_f32(h[0], h[1], 0, false);
                w = __builtin_amdgcn_cvt_pk_fp8_f32(h[2], h[3], w, true);
                *(unsigned int*)(out8 + base) = (unsigned int)w;
            }
        }
    }
}

// ---------------- mean aggregation: fp8 table, 4x16 4-deep pipeline (R10) ----
// x8: fp8 e4m3, row-major [node][128]. lane (e4,c16): 4 edge-groups x
// 16 feat-lanes; uint2 = 8 fp8 feats at c16*8. Unroll x4: 16 rows in flight.
__global__ void k_agg(const uint2* __restrict__ x8_2, const int* __restrict__ rowptr,
                      const int* __restrict__ col, const float* __restrict__ inv_deg,
                      uint4* __restrict__ aggb4, int n) {
    int node = (blockIdx.x * blockDim.x + threadIdx.x) >> 6;
    int lane = threadIdx.x & 63;
    if (node >= n) return;
    const int e4 = lane >> 4, c16 = lane & 15;
    const int lo = rowptr[node], hi = rowptr[node + 1];

    float a0 = 0.f, a1 = 0.f, a2 = 0.f, a3 = 0.f,
          a4 = 0.f, a5 = 0.f, a6 = 0.f, a7 = 0.f;

    int i0 = lo + e4;
    int s0 = (i0      < hi) ? col[i0]      : -1;
    int s1 = (i0 + 4  < hi) ? col[i0 + 4]  : -1;
    int s2 = (i0 + 8  < hi) ? col[i0 + 8]  : -1;
    int s3 = (i0 + 12 < hi) ? col[i0 + 12] : -1;

    for (int j = lo; j < hi; j += 16) {
        uint2 v0 = x8_2[(size_t)(s0 > 0 ? s0 : 0) * 16 + c16];
        uint2 v1 = x8_2[(size_t)(s1 > 0 ? s1 : 0) * 16 + c16];
        uint2 v2 = x8_2[(size_t)(s2 > 0 ? s2 : 0) * 16 + c16];
        uint2 v3 = x8_2[(size_t)(s3 > 0 ? s3 : 0) * 16 + c16];
        float m0 = s0 >= 0 ? 1.f : 0.f;
        float m1 = s1 >= 0 ? 1.f : 0.f;
        float m2 = s2 >= 0 ? 1.f : 0.f;
        float m3 = s3 >= 0 ? 1.f : 0.f;
        int nj = j + 16 + e4;
        s0 = (nj      < hi) ? col[nj]      : -1;
        s1 = (nj + 4  < hi) ? col[nj + 4]  : -1;
        s2 = (nj + 8  < hi) ? col[nj + 8]  : -1;
        s3 = (nj + 12 < hi) ? col[nj + 12] : -1;
#define ACC_(v, m)                                                            \
        {                                                                     \
            f32x2 f01 = __builtin_amdgcn_cvt_pk_f32_fp8(v.x, false);          \
            f32x2 f23 = __builtin_amdgcn_cvt_pk_f32_fp8(v.x, true);           \
            f32x2 f45 = __builtin_amdgcn_cvt_pk_f32_fp8(v.y, false);          \
            f32x2 f67 = __builtin_amdgcn_cvt_pk_f32_fp8(v.y, true);           \
            a0 = fmaf(f01.x, m, a0); a1 = fmaf(f01.y, m, a1);                 \
            a2 = fmaf(f23.x, m, a2); a3 = fmaf(f23.y, m, a3);                 \
            a4 = fmaf(f45.x, m, a4); a5 = fmaf(f45.y, m, a5);                 \
            a6 = fmaf(f67.x, m, a6); a7 = fmaf(f67.y, m, a7);                 \
        }
        ACC_(v0, m0) ACC_(v1, m1) ACC_(v2, m2) ACC_(v3, m3)
#undef ACC_
    }
#define RED_(a) a += __shfl_xor(a, 16); a += __shfl_xor(a, 32);
    RED_(a0) RED_(a1) RED_(a2) RED_(a3) RED_(a4) RED_(a5) RED_(a6) RED_(a7)
#undef RED_
    float sc = inv_deg[node];
    uint4 o;
    o.x = pack2(a0 * sc, a1 * sc);
    o.y = pack2(a2 * sc, a3 * sc);
    o.z = pack2(a4 * sc, a5 * sc);
    o.w = pack2(a6 * sc, a7 * sc);
    if (lane < 16) aggb4[(size_t)node * 16 + c16] = o;
}

// ---------------- MFMA dual-GEMM: async W staging + hoisted A loads ----------
// block = 256 thr = 4 waves; wave = 16 nodes x 128 feats; grid = N/64.
__global__ __launch_bounds__(256) void k_gemm(
    const unsigned short* __restrict__ A0, const unsigned short* __restrict__ A1,
    const unsigned short* __restrict__ Wf0, const unsigned short* __restrict__ Wf1,
    const float* __restrict__ bias,
    const float* __restrict__ gamma, const float* __restrict__ beta,
    const float* __restrict__ mean, const float* __restrict__ var,
    const unsigned short* __restrict__ residb,
    float* __restrict__ out32, unsigned short* __restrict__ outb,
    unsigned char* __restrict__ out8, int nrows) {
    __shared__ unsigned short wlds[16384];  // 32 KB: one segment's frags
    __shared__ float colp[2 * DIM];         // per-col (scale, shift)

    const int tid = threadIdx.x;
    const int lane = tid & 63;
    const int l15 = lane & 15;
    const int lhi = lane >> 4;
    const int wave = tid >> 6;
    const int node = blockIdx.x * 64 + wave * 16 + l15;
    const int arow = node < nrows ? node : nrows - 1;  // clamped read row

    // ---- issue A0 fragment loads first (latency under staging+barrier) ----
    bf16x8 af0[4];
    {
        const unsigned short* a0 = A0 + (size_t)arow * DIM + lhi * 8;
#pragma unroll
        for (int k = 0; k < 4; ++k) af0[k] = *(const bf16x8*)(a0 + k * 32);
    }

    // ---- stage seg0 W frags: async DMA, 8 x 1KB per wave, linear ----
    {
        const unsigned short* g = Wf0 + (size_t)wave * 4096 + lane * 8;
#pragma unroll
        for (int i = 0; i < 8; ++i)
            GLOAD_LDS16(g + i * 512, &wlds[wave * 4096 + i * 512]);
    }

    if (tid < DIM) {
        float s = gamma[tid] * rsqrtf(var[tid] + BN_EPS);
        colp[tid * 2] = s;
        colp[tid * 2 + 1] = (bias[tid] - mean[tid]) * s + beta[tid];
    }

    f32x4 acc[8];
#pragma unroll
    for (int ct = 0; ct < 8; ++ct) acc[ct] = (f32x4){0.f, 0.f, 0.f, 0.f};

    __syncthreads();  // W0 in LDS (barrier drains vmcnt)

    // ---- issue A1 loads now: latency hides under seg0 MFMAs ----
    bf16x8 af1[4];
    {
        const unsigned short* a1 = A1 + (size_t)arow * DIM + lhi * 8;
#pragma unroll
        for (int k = 0; k < 4; ++k) af1[k] = *(const bf16x8*)(a1 + k * 32);
    }

    // ---- seg0 compute ----
#pragma unroll
    for (int k = 0; k < 4; ++k) {
        bf16x8 bw[8];
#pragma unroll
        for (int ct = 0; ct < 8; ++ct)
            bw[ct] = *(const bf16x8*)&wlds[((ct * 4 + k) * 64 + lane) * 8];
#pragma unroll
        for (int ct = 0; ct < 8; ++ct)
            acc[ct] = __builtin_amdgcn_mfma_f32_16x16x32_bf16(bw[ct], af0[k],
                                                              acc[ct], 0, 0, 0);
    }

    __syncthreads();  // all waves done reading W0
    {
        const unsigned short* g = Wf1 + (size_t)wave * 4096 + lane * 8;
#pragma unroll
        for (int i = 0; i < 8; ++i)
            GLOAD_LDS16(g + i * 512, &wlds[wave * 4096 + i * 512]);
    }
    __syncthreads();  // W1 in LDS
#pragma unroll
    for (int k = 0; k < 4; ++k) {
        bf16x8 bw[8];
#pragma unroll
        for (int ct = 0; ct < 8; ++ct)
            bw[ct] = *(const bf16x8*)&wlds[((ct * 4 + k) * 64 + lane) * 8];
#pragma unroll
        for (int ct = 0; ct < 8; ++ct)
            acc[ct] = __builtin_amdgcn_mfma_f32_16x16x32_bf16(bw[ct], af1[k],
                                                              acc[ct], 0, 0, 0);
    }

    // ---- epilogue: thread owns feats ct*16+lhi*4..+3 of node ----
    if (node < nrows) {
#pragma unroll
        for (int ct = 0; ct < 8; ++ct) {
            int c0 = ct * 16 + lhi * 4;
            float h[4];
#pragma unroll
            for (int j = 0; j < 4; ++j) {
                float2 p = *(const float2*)&colp[(c0 + j) * 2];
                h[j] = fmaxf(acc[ct][j] * p.x + p.y, 0.f);
            }
            size_t base = (size_t)node * DIM + c0;
            if (residb) {
                uint2 rv = *(const uint2*)(residb + base);
                h[0] += bf_e0(rv.x); h[1] += bf_e1(rv.x);
                h[2] += bf_e0(rv.y); h[3] += bf_e1(rv.y);
            }
            if (outb) {
                uint2 o;
                o.x = pack2(h[0], h[1]);
                o.y = pack2(h[2], h[3]);
                *(uint2*)(outb + base) = o;
            }
            if (out8) {
                int w = __builtin_amdgcn_cvt_pk_fp8_f32(h[0], h[1], 0, false);
                w = __builtin_amdgcn_cvt_pk_fp8_f32(h[2], h[3], w, true);
                *(unsigned int*)(out8 + base) = (unsigned int)w;
            }
            if (out32)
                *(float4*)(out32 + base) = make_float4(h[0], h[1], h[2], h[3]);
        }
    }
}

extern "C" void kernel_launch(void* const* d_in, const int* in_sizes, int n_in,
                              void* d_out, int out_size, void* d_ws, size_t ws_size,
                              hipStream_t stream) {
    const float* x_in = (const float*)d_in[0];
    const int* ei     = (const int*)d_in[1];
    const float* Wp   = (const float*)d_in[2];
    const float* bp   = (const float*)d_in[3];
    const float* Wl   = (const float*)d_in[4];
    const float* bl   = (const float*)d_in[5];
    const float* Wr   = (const float*)d_in[6];
    const float* g    = (const float*)d_in[7];
    const float* be   = (const float*)d_in[8];
    const float* mu   = (const float*)d_in[9];
    const float* va   = (const float*)d_in[10];

    const int N = in_sizes[0] / DIM;
    const int E = in_sizes[1] / 2;
    const int* src = ei;
    const int* dst = ei + E;
    const int NB = (N + 255) >> 8;  // 256-node buckets

    // ---- workspace carve (256B aligned) ----
    char* p = (char*)d_ws;
    auto alloc = [&](size_t bytes) {
        char* r = p;
        p += (bytes + 255) & ~(size_t)255;
        return r;
    };
    float* inv_deg = (float*)alloc((size_t)N * 4);
    int* rowptr    = (int*)alloc((size_t)(N + 1) * 4);
    int* cursor    = (int*)alloc((size_t)NB * 4);
    int* col       = (int*)alloc((size_t)E * 4);
    unsigned int* binned = (unsigned int*)alloc((size_t)NB * BCAP * 4);
    unsigned short* xb   = (unsigned short*)alloc((size_t)N * DIM * 2);
    unsigned char* x8    = (unsigned char*)alloc((size_t)N * DIM);
    unsigned short* aggb = (unsigned short*)alloc((size_t)N * DIM * 2);
    unsigned short* WTf  = (unsigned short*)alloc((size_t)9 * 16384 * 2);

    const int gblocks = (N + 63) / 64;

    // ---- CSR build pass 1 (k_bin also transforms weights in tail blocks) ----
    hipMemsetAsync(cursor, 0, (size_t)NB * 4, stream);
    k_bin<<<(E + EPB - 1) / EPB, 256, 0, stream>>>(src, dst, cursor, binned,
                                                   Wp, Wl, Wr, WTf, E, NB);

    // ---- pass 2: CSR fill (blocks 0..NB) + projection GEMM (rest) merged ----
    k_csr_proj<<<NB + gblocks, 256, 0, stream>>>(cursor, binned, rowptr, inv_deg,
                                                 col, N, NB,
                                                 x_in, WTf, bp, xb, x8);

    float* out = (float*)d_out;
    for (int i = 0; i < 4; ++i) {
        k_agg<<<(N + 3) / 4, 256, 0, stream>>>((const uint2*)x8, rowptr, col,
                                               inv_deg, (uint4*)aggb, N);
        const unsigned short* WlF = WTf + (size_t)(1 + i) * 16384;
        const unsigned short* WrF = WTf + (size_t)(5 + i) * 16384;
        // layers 0..2: xb/x8 = bf16/fp8(xb + relu(bn(h)));  layer 3: out fp32
        k_gemm<<<gblocks, 256, 0, stream>>>(
            aggb, xb, WlF, WrF, bl + i * DIM,
            g + i * DIM, be + i * DIM, mu + i * DIM, va + i * DIM,
            (i < 3) ? xb : nullptr,
            (i < 3) ? nullptr : out, (i < 3) ? xb : nullptr,
            (i < 3) ? x8 : nullptr, N);
    }
}